// Round 10
// baseline (852.823 us; speedup 1.0000x reference)
//
#include <hip/hip_runtime.h>
#include <stdint.h>

// Problem constants (fixed by reference)
#define D_MODEL   768
#define D_INNER   1536
#define D_STATE   16
#define DT_RANK   48
#define NB        4
#define TSEQ      1024
#define NTOK      4096         // NB*TSEQ
#define EPS       1e-5f
#define CHUNK     16           // scan chunk length (16: doubles wave count vs 32 -> latency hiding)
#define NCHUNK    64           // TSEQ/CHUNK
#define XP_N      128          // x_proj output padded 80 -> 128 for MFMA tile

typedef __bf16 bf16;
typedef __bf16 bf16x8 __attribute__((ext_vector_type(8)));
typedef float  floatx4 __attribute__((ext_vector_type(4)));
typedef float  f32x2   __attribute__((ext_vector_type(2)));

__device__ __forceinline__ float silu_f(float v)     { return v / (1.f + __expf(-v)); }
__device__ __forceinline__ float softplus_f(float v) { return v > 20.f ? v : __logf(1.f + __expf(v)); }

// async global->LDS, 16B per lane; LDS dest is wave-uniform base + lane*16
__device__ __forceinline__ void async_ld16(const void* g, void* l) {
  __builtin_amdgcn_global_load_lds((__attribute__((address_space(1))) uint32_t*)g,
                                   (__attribute__((address_space(3))) uint32_t*)l, 16, 0, 0);
}

__device__ __forceinline__ bf16x8 cvt8(const float* __restrict__ s) {
  const float4 a = *(const float4*)s, b = *(const float4*)(s + 4);
  bf16x8 o;
  o[0] = (bf16)a.x; o[1] = (bf16)a.y; o[2] = (bf16)a.z; o[3] = (bf16)a.w;
  o[4] = (bf16)b.x; o[5] = (bf16)b.y; o[6] = (bf16)b.z; o[7] = (bf16)b.w;
  return o;
}

// ---------------------------------------------------------------- mega-prep: weight casts + input projection
// blocks [0, 6912): in/out proj weights fp32->bf16, 8 elems/thread (float4 x2 -> bf16x8 16B store)
// blocks [6912, 7296): x_proj weight pad 80->128 rows, 8 elems/thread
// blocks [7296, 19584): input projection (K=12) -> h, 1 elem/thread
__global__ __launch_bounds__(256) void prep_k(const float* __restrict__ win, const float* __restrict__ wout,
                                              const float* __restrict__ wxp,
                                              const float* __restrict__ x, const float* __restrict__ inw,
                                              const float* __restrict__ inb,
                                              bf16* __restrict__ bin, bf16* __restrict__ bout,
                                              bf16* __restrict__ bxp, float* __restrict__ h) {
  const int blk = blockIdx.x;
  if (blk < 6912) {
    const int i8 = blk * 2048 + threadIdx.x * 8;        // NIN = 9437184 = 4608 blocks exactly
    const int NIN = 4 * 3072 * 768;
    if (i8 < NIN) *(bf16x8*)&bin[i8] = cvt8(win + i8);
    else          *(bf16x8*)&bout[i8 - NIN] = cvt8(wout + (i8 - NIN));
  } else if (blk < 7296) {
    const int i8 = (blk - 6912) * 2048 + threadIdx.x * 8;   // 4*128*1536; 8 elems same row
    const int k = i8 % 1536;
    const int r = (i8 / 1536) % XP_N;
    const int l = i8 / (1536 * XP_N);
    if (r < 80) *(bf16x8*)&bxp[i8] = cvt8(wxp + ((size_t)l * 80 + r) * 1536 + k);
    else        *(bf16x8*)&bxp[i8] = (bf16x8){(bf16)0.f, (bf16)0.f, (bf16)0.f, (bf16)0.f,
                                              (bf16)0.f, (bf16)0.f, (bf16)0.f, (bf16)0.f};
  } else {
    const int idx = (blk - 7296) * 256 + threadIdx.x;   // NTOK*768
    const int d = idx % D_MODEL;
    const int t = idx / D_MODEL;
    float acc = inb[d];
    #pragma unroll
    for (int f = 0; f < 12; ++f) acc = fmaf(x[t * 12 + f], inw[d * 12 + f], acc);
    h[idx] = acc;
  }
}

// ---------------------------------------------------------------- rmsnorm -> bf16
__global__ __launch_bounds__(256) void rmsnorm_k(const float* __restrict__ h, const float* __restrict__ lnw,
                                                 bf16* __restrict__ xn) {
  const int t = blockIdx.x;
  const float* __restrict__ hr = h + (size_t)t * D_MODEL;
  float v[3];
  float ss = 0.f;
  #pragma unroll
  for (int i = 0; i < 3; ++i) { v[i] = hr[threadIdx.x + i * 256]; ss = fmaf(v[i], v[i], ss); }
  #pragma unroll
  for (int o = 32; o > 0; o >>= 1) ss += __shfl_down(ss, o, 64);
  __shared__ float red[4];
  if ((threadIdx.x & 63) == 0) red[threadIdx.x >> 6] = ss;
  __syncthreads();
  const float tot = red[0] + red[1] + red[2] + red[3];
  const float rs = rsqrtf(tot / (float)D_MODEL + EPS);
  #pragma unroll
  for (int i = 0; i < 3; ++i) {
    const int d = threadIdx.x + i * 256;
    xn[(size_t)t * D_MODEL + d] = (bf16)(v[i] * rs * lnw[d]);
  }
}

// ---------------------------------------------------------------- bf16 MFMA GEMM: C[4096,N] (+)= A[4096,K] @ B[N,K]^T
// m97 layout, BK=64: two 128x32 half-tiles per matrix staged per barrier pair
// (second half at +8KB), 32 MFMAs per iter -> half the vmcnt(0)+barrier drains.
// MODE: 1 = bf16 overwrite, 2 = fp32 atomicAdd (split-K via blockIdx.z). kLen % 64 == 0.
template <int MODE>
__global__ __launch_bounds__(256) void gemm_bt(const bf16* __restrict__ A, const bf16* __restrict__ B,
                                               void* __restrict__ Cv, const int N, const int K, const int kLen) {
  alignas(16) __shared__ bf16 As[2 * 128 * 32];    // [half][128][32]
  alignas(16) __shared__ bf16 Bs[2 * 128 * 32];
  const int tid = threadIdx.x;
  const int lane = tid & 63;
  const int wid = tid >> 6;
  const int wm = wid & 1, wn = wid >> 1;
  const int m0 = blockIdx.x * 128, n0 = blockIdx.y * 128;
  const int kOff = blockIdx.z * kLen;

  floatx4 acc[4][4];
  #pragma unroll
  for (int i = 0; i < 4; ++i)
    #pragma unroll
    for (int j = 0; j < 4; ++j) acc[i][j] = (floatx4){0.f, 0.f, 0.f, 0.f};

  const int srow = lane >> 2;          // staging: row within 16-row segment
  const int skp  = (lane & 3) * 8;     // staging: k offset (8 bf16 = 16B)
  const int fr = lane & 15;            // fragment row
  const int fk = (lane >> 4) * 8;      // fragment k

  for (int k0 = 0; k0 < kLen; k0 += 64) {
    __syncthreads();                   // all waves done reading LDS from prev iter
    #pragma unroll
    for (int h = 0; h < 2; ++h) {      // two k-halves, each the proven 128x32 layout
      #pragma unroll
      for (int i = 0; i < 2; ++i) {
        const int seg = wid * 2 + i;   // 8 segments x 1KB per half-matrix
        const int row = seg * 16 + srow;
        const int kg = kOff + k0 + h * 32 + skp;
        async_ld16(A + (size_t)(m0 + row) * K + kg, (char*)As + h * 8192 + seg * 1024);
        async_ld16(B + (size_t)(n0 + row) * K + kg, (char*)Bs + h * 8192 + seg * 1024);
      }
    }
    __syncthreads();                   // compiler drains vmcnt(0) before barrier
    #pragma unroll
    for (int h = 0; h < 2; ++h) {
      bf16x8 a[4], b[4];
      #pragma unroll
      for (int t = 0; t < 4; ++t) {
        a[t] = *(const bf16x8*)&As[h * 4096 + (wm * 64 + t * 16 + fr) * 32 + fk];
        b[t] = *(const bf16x8*)&Bs[h * 4096 + (wn * 64 + t * 16 + fr) * 32 + fk];
      }
      #pragma unroll
      for (int i = 0; i < 4; ++i)
        #pragma unroll
        for (int j = 0; j < 4; ++j)
          acc[i][j] = __builtin_amdgcn_mfma_f32_16x16x32_bf16(a[i], b[j], acc[i][j], 0, 0, 0);
    }
  }

  const int quad = lane >> 4, col = lane & 15;
  #pragma unroll
  for (int i = 0; i < 4; ++i)
    #pragma unroll
    for (int j = 0; j < 4; ++j) {
      const int gm0 = m0 + wm * 64 + i * 16 + quad * 4;
      const int gn  = n0 + wn * 64 + j * 16 + col;
      #pragma unroll
      for (int r = 0; r < 4; ++r) {
        const size_t off = (size_t)(gm0 + r) * N + gn;
        const float v = acc[i][j][r];
        if (MODE == 1) ((bf16*)Cv)[off] = (bf16)v;
        else           atomicAdd(&((float*)Cv)[off], v);
      }
    }
}

// ---------------------------------------------------------------- causal depthwise conv4 + silu (bf16 in/out)
// blocks [0,512) additionally zero the dbc accumulator (2 MB) for the following split-K GEMM.
__global__ __launch_bounds__(256) void conv_silu_k(const bf16* __restrict__ xz, const float* __restrict__ cw,
                                                   const float* __restrict__ cb, bf16* __restrict__ xxb,
                                                   float* __restrict__ dbc) {
  if (blockIdx.x < 512) {
    const int z = blockIdx.x * 256 + threadIdx.x;      // 131072 float4 = 2 MB
    ((float4*)dbc)[z] = (float4){0.f, 0.f, 0.f, 0.f};
  }
  const int idx = blockIdx.x * 256 + threadIdx.x;   // NTOK*1536
  const int d = idx % D_INNER;
  const int bt = idx / D_INNER;
  const int t = bt & (TSEQ - 1);
  float acc = cb[d];
  #pragma unroll
  for (int j = 0; j < 4; ++j) {
    const int tt = t - 3 + j;
    if (tt >= 0) acc = fmaf((float)xz[(size_t)(bt - 3 + j) * (2 * D_INNER) + d], cw[d * 4 + j], acc);
  }
  xxb[idx] = (bf16)silu_f(acc);
}

// ---------------------------------------------------------------- chunked selective scan, phase 1 (+fused dt_proj):
// packed-fp32 (v_pk_fma_f32) version. per chunk: su = sum du_t, S[n] local state; stores delta for p3.
// Fast path exploits A_log = log(1..16) => A_n = -(n+1): e_n = r^(n+1), pairs E_k=(r^{2k+1},r^{2k+2}).
__global__ __launch_bounds__(256) void scan_p1_k(const bf16* __restrict__ xxb, const float* __restrict__ dbc,
                                                 const float* __restrict__ dtw, const float* __restrict__ dtb,
                                                 const float* __restrict__ Alog,
                                                 float* __restrict__ S, float* __restrict__ su,
                                                 float* __restrict__ delta) {
  const int c = blockIdx.x;
  const int d = blockIdx.y * 256 + threadIdx.x;
  const int b = blockIdx.z;
  f32x2 w2[24];
  #pragma unroll
  for (int k = 0; k < 12; ++k) {
    const float4 t4 = *(const float4*)&dtw[(size_t)d * DT_RANK + k * 4];
    w2[2 * k]     = (f32x2){t4.x, t4.y};
    w2[2 * k + 1] = (f32x2){t4.z, t4.w};
  }
  const float bias = dtb[d];
  float A[16];
  bool fast = true;
  #pragma unroll
  for (int n = 0; n < 16; ++n) {
    A[n] = -__expf(Alog[(size_t)d * 16 + n]);
    fast = fast && (__builtin_fabsf(A[n] + (float)(n + 1)) < 1e-3f);
  }
  f32x2 S2[8];
  #pragma unroll
  for (int k = 0; k < 8; ++k) S2[k] = (f32x2){0.f, 0.f};
  float sus = 0.f;
  const int bt0 = b * TSEQ + c * CHUNK;
  if (fast) {
    for (int tt = 0; tt < CHUNK; ++tt) {
      const size_t bt = bt0 + tt;
      const float* __restrict__ db = dbc + bt * XP_N;             // wave-uniform -> s_load
      f32x2 acc2 = (f32x2){bias, 0.f};
      #pragma unroll
      for (int k = 0; k < 24; ++k) acc2 += *(const f32x2*)&db[2 * k] * w2[k];   // v_pk_fma_f32
      const float du = softplus_f(acc2.x + acc2.y);
      delta[bt * D_INNER + d] = du;
      sus += du;
      const float xv  = (float)xxb[bt * D_INNER + d];
      const float dux = du * xv;
      const f32x2 dux2 = (f32x2){dux, dux};
      const float r  = __expf(-du);
      const float rr = r * r;
      f32x2 E = (f32x2){r, rr};
      const f32x2 F = (f32x2){rr, rr};
      const f32x2* __restrict__ B2 = (const f32x2*)(db + DT_RANK);
      #pragma unroll
      for (int k = 0; k < 8; ++k) {
        S2[k] = E * S2[k] + dux2 * B2[k];
        E *= F;
      }
    }
  } else {
    for (int tt = 0; tt < CHUNK; ++tt) {
      const size_t bt = bt0 + tt;
      const float* __restrict__ db = dbc + bt * XP_N;
      float dacc = bias;
      #pragma unroll
      for (int k = 0; k < 24; ++k) { dacc = fmaf(db[2*k], w2[k].x, dacc); dacc = fmaf(db[2*k+1], w2[k].y, dacc); }
      const float du = softplus_f(dacc);
      delta[bt * D_INNER + d] = du;
      sus += du;
      const float xv  = (float)xxb[bt * D_INNER + d];
      const float dux = du * xv;
      const float* __restrict__ Bp = db + DT_RANK;
      #pragma unroll
      for (int n = 0; n < 16; ++n) {
        float* sv = (float*)&S2[n >> 1];
        sv[n & 1] = fmaf(__expf(du * A[n]), sv[n & 1], dux * Bp[n]);
      }
    }
  }
  const size_t base = ((size_t)(b * NCHUNK + c) * 16) * D_INNER + d;
  #pragma unroll
  for (int n = 0; n < 16; ++n) S[base + (size_t)n * D_INNER] = ((const float*)&S2[n >> 1])[n & 1];
  su[(size_t)(b * NCHUNK + c) * D_INNER + d] = sus;
}

// ---------------------------------------------------------------- phase 2: sequential chunk-prefix fold
// one thread per (b, n, d); P_c = exp(A_n * su_c) (math identity); S <- Hin in place.
__global__ __launch_bounds__(256) void scan_fold_k(const float* __restrict__ Alog, const float* __restrict__ su,
                                                   float* __restrict__ S) {
  const int idx = blockIdx.x * 256 + threadIdx.x;       // NB*16*D_INNER = 98304
  const int d = idx % D_INNER;
  const int bn = idx / D_INNER;
  const int n = bn & 15;
  const int b = bn >> 4;
  const float A = -__expf(Alog[(size_t)d * 16 + n]);
  float H = 0.f;
  #pragma unroll 4
  for (int c = 0; c < NCHUNK; ++c) {
    const size_t off = ((size_t)((b * NCHUNK + c) * 16 + n)) * D_INNER + d;
    const float Pv = __expf(A * su[(size_t)(b * NCHUNK + c) * D_INNER + d]);
    const float Sv = S[off];
    S[off] = H;                       // S becomes Hin (incoming state for chunk c)
    H = fmaf(Pv, H, Sv);
  }
}

// phase 3: packed-fp32 replay with incoming state + precomputed delta; fuse D-skip + silu(z) gate; emit bf16
__global__ __launch_bounds__(256) void scan_p3_k(const bf16* __restrict__ xxb, const float* __restrict__ dbc,
                                                 const float* __restrict__ delta, const float* __restrict__ Alog,
                                                 const float* __restrict__ Hin,
                                                 const bf16* __restrict__ xz, const float* __restrict__ Dsk,
                                                 bf16* __restrict__ yg) {
  const int c = blockIdx.x;
  const int d = blockIdx.y * 256 + threadIdx.x;
  const int b = blockIdx.z;
  const size_t hbase = ((size_t)(b * NCHUNK + c) * 16) * D_INNER + d;
  float A[16];
  f32x2 H2[8];
  bool fast = true;
  #pragma unroll
  for (int n = 0; n < 16; ++n) {
    A[n] = -__expf(Alog[(size_t)d * 16 + n]);
    fast = fast && (__builtin_fabsf(A[n] + (float)(n + 1)) < 1e-3f);
    ((float*)&H2[n >> 1])[n & 1] = Hin[hbase + (size_t)n * D_INNER];
  }
  const float dsk = Dsk[d];
  const int bt0 = b * TSEQ + c * CHUNK;
  if (fast) {
    for (int tt = 0; tt < CHUNK; ++tt) {
      const size_t bt = bt0 + tt;
      const float du  = delta[bt * D_INNER + d];
      const float xv  = (float)xxb[bt * D_INNER + d];
      const float dux = du * xv;
      const f32x2 dux2 = (f32x2){dux, dux};
      const float* __restrict__ db = dbc + bt * XP_N;             // wave-uniform -> s_load
      const f32x2* __restrict__ B2 = (const f32x2*)(db + DT_RANK);
      const f32x2* __restrict__ C2 = (const f32x2*)(db + DT_RANK + 16);
      const float r  = __expf(-du);
      const float rr = r * r;
      f32x2 E = (f32x2){r, rr};
      const f32x2 F = (f32x2){rr, rr};
      f32x2 y2 = (f32x2){0.f, 0.f};
      #pragma unroll
      for (int k = 0; k < 8; ++k) {
        H2[k] = E * H2[k] + dux2 * B2[k];
        y2 = H2[k] * C2[k] + y2;
        E *= F;
      }
      const float y = y2.x + y2.y;
      const float z = (float)xz[bt * (2 * D_INNER) + D_INNER + d];
      yg[bt * D_INNER + d] = (bf16)((y + dsk * xv) * silu_f(z));
    }
  } else {
    for (int tt = 0; tt < CHUNK; ++tt) {
      const size_t bt = bt0 + tt;
      const float du  = delta[bt * D_INNER + d];
      const float xv  = (float)xxb[bt * D_INNER + d];
      const float dux = du * xv;
      const float* __restrict__ db = dbc + bt * XP_N;
      const float* __restrict__ Bp = db + DT_RANK;
      const float* __restrict__ Cp = db + DT_RANK + 16;
      float y = 0.f;
      #pragma unroll
      for (int n = 0; n < 16; ++n) {
        float* hv = (float*)&H2[n >> 1];
        hv[n & 1] = fmaf(__expf(du * A[n]), hv[n & 1], dux * Bp[n]);
        y = fmaf(hv[n & 1], Cp[n], y);
      }
      const float z = (float)xz[bt * (2 * D_INNER) + D_INNER + d];
      yg[bt * D_INNER + d] = (bf16)((y + dsk * xv) * silu_f(z));
    }
  }
}

// ---------------------------------------------------------------- final rmsnorm + head dot
__global__ __launch_bounds__(256) void final_k(const float* __restrict__ h, const float* __restrict__ nw,
                                               const float* __restrict__ hw, const float* __restrict__ hb,
                                               float* __restrict__ out) {
  const int t = blockIdx.x;
  const float* __restrict__ hr = h + (size_t)t * D_MODEL;
  float ss = 0.f, dt_ = 0.f;
  #pragma unroll
  for (int i = 0; i < 3; ++i) {
    const int d = threadIdx.x + i * 256;
    const float v = hr[d];
    ss  = fmaf(v, v, ss);
    dt_ = fmaf(v, nw[d] * hw[d], dt_);
  }
  #pragma unroll
  for (int o = 32; o > 0; o >>= 1) { ss += __shfl_down(ss, o, 64); dt_ += __shfl_down(dt_, o, 64); }
  __shared__ float r0[4], r1[4];
  if ((threadIdx.x & 63) == 0) { r0[threadIdx.x >> 6] = ss; r1[threadIdx.x >> 6] = dt_; }
  __syncthreads();
  if (threadIdx.x == 0) {
    const float sst = r0[0] + r0[1] + r0[2] + r0[3];
    const float dtt = r1[0] + r1[1] + r1[2] + r1[3];
    out[t] = dtt * rsqrtf(sst / (float)D_MODEL + EPS) + hb[0];
  }
}

// ---------------------------------------------------------------- host orchestration
extern "C" void kernel_launch(void* const* d_in, const int* in_sizes, int n_in,
                              void* d_out, int out_size, void* d_ws, size_t ws_size,
                              hipStream_t stream) {
  (void)in_sizes; (void)n_in; (void)out_size; (void)ws_size;
  const float* x     = (const float*)d_in[0];
  const float* inpw  = (const float*)d_in[1];
  const float* inpb  = (const float*)d_in[2];
  const float* inprj = (const float*)d_in[3];
  const float* convw = (const float*)d_in[4];
  const float* convb = (const float*)d_in[5];
  const float* xprjw = (const float*)d_in[6];
  const float* dtw   = (const float*)d_in[7];
  const float* dtb   = (const float*)d_in[8];
  const float* alog  = (const float*)d_in[9];
  const float* dskip = (const float*)d_in[10];
  const float* outw  = (const float*)d_in[11];
  const float* lnw   = (const float*)d_in[12];
  const float* normw = (const float*)d_in[13];
  const float* headw = (const float*)d_in[14];
  const float* headb = (const float*)d_in[15];
  float* out = (float*)d_out;

  // workspace layout (~170 MB used of the fixed allocation)
  char* p = (char*)d_ws;
  auto take = [&](size_t bytes) { char* q = p; p += (bytes + 255) & ~(size_t)255; return q; };
  bf16*  wbin  = (bf16*) take((size_t)4 * 3072 * 768 * 2);
  bf16*  wbout = (bf16*) take((size_t)4 * 768 * 1536 * 2);
  bf16*  wbxp  = (bf16*) take((size_t)4 * XP_N * 1536 * 2);
  float* h     = (float*)take((size_t)NTOK * D_MODEL * 4);
  bf16*  xn    = (bf16*) take((size_t)NTOK * D_MODEL * 2);
  bf16*  xzb   = (bf16*) take((size_t)NTOK * 2 * D_INNER * 2);
  bf16*  xxb   = (bf16*) take((size_t)NTOK * D_INNER * 2);
  float* dbc   = (float*)take((size_t)NTOK * XP_N * 4);
  float* dlt   = (float*)take((size_t)NTOK * D_INNER * 4);
  float* Sb    = (float*)take((size_t)NB * NCHUNK * 16 * D_INNER * 4);   // becomes Hin in fold
  float* su    = (float*)take((size_t)NB * NCHUNK * D_INNER * 4);
  bf16*  yg    = (bf16*) take((size_t)NTOK * D_INNER * 2);

  prep_k<<<19584, 256, 0, stream>>>(inprj, outw, xprjw, x, inpw, inpb, wbin, wbout, wbxp, h);

  for (int l = 0; l < 4; ++l) {
    rmsnorm_k<<<NTOK, 256, 0, stream>>>(h, lnw + l * D_MODEL, xn);
    gemm_bt<1><<<dim3(32, 24, 1), 256, 0, stream>>>(xn, wbin + (size_t)l * 3072 * 768, xzb, 3072, 768, 768);
    conv_silu_k<<<NTOK * D_INNER / 256, 256, 0, stream>>>(xzb, convw + l * D_INNER * 4, convb + l * D_INNER,
                                                          xxb, dbc);
    gemm_bt<2><<<dim3(32, 1, 8), 256, 0, stream>>>(xxb, wbxp + (size_t)l * XP_N * 1536, dbc, XP_N, 1536, 192);
    scan_p1_k<<<dim3(NCHUNK, 6, NB), 256, 0, stream>>>(xxb, dbc, dtw + (size_t)l * D_INNER * DT_RANK,
                                                       dtb + l * D_INNER, alog + (size_t)l * D_INNER * 16,
                                                       Sb, su, dlt);
    scan_fold_k<<<NB * 16 * D_INNER / 256, 256, 0, stream>>>(alog + (size_t)l * D_INNER * 16, su, Sb);
    scan_p3_k<<<dim3(NCHUNK, 6, NB), 256, 0, stream>>>(xxb, dbc, dlt, alog + (size_t)l * D_INNER * 16,
                                                       Sb, xzb, dskip + l * D_INNER, yg);
    gemm_bt<2><<<dim3(32, 6, 2), 256, 0, stream>>>(yg, wbout + (size_t)l * 768 * 1536, h, 768, 1536, 768);
  }

  final_k<<<NTOK, 256, 0, stream>>>(h, normw, headw, headb, out);
}

// Round 11
// 816.543 us; speedup vs baseline: 1.0444x; 1.0444x over previous
//
#include <hip/hip_runtime.h>
#include <stdint.h>

// Problem constants (fixed by reference)
#define D_MODEL   768
#define D_INNER   1536
#define D_STATE   16
#define DT_RANK   48
#define NB        4
#define TSEQ      1024
#define NTOK      4096         // NB*TSEQ
#define EPS       1e-5f
#define CHUNK     32           // scan chunk length (32 proven best: 16 doubled fold/epilogue cost — R9)
#define NCHUNK    32           // TSEQ/CHUNK
#define XP_N      128          // x_proj output padded 80 -> 128 for MFMA tile

typedef __bf16 bf16;
typedef __bf16 bf16x8 __attribute__((ext_vector_type(8)));
typedef float  floatx4 __attribute__((ext_vector_type(4)));
typedef float  f32x2   __attribute__((ext_vector_type(2)));

__device__ __forceinline__ float silu_f(float v)     { return v / (1.f + __expf(-v)); }
__device__ __forceinline__ float softplus_f(float v) { return v > 20.f ? v : __logf(1.f + __expf(v)); }

// async global->LDS, 16B per lane; LDS dest is wave-uniform base + lane*16
__device__ __forceinline__ void async_ld16(const void* g, void* l) {
  __builtin_amdgcn_global_load_lds((__attribute__((address_space(1))) uint32_t*)g,
                                   (__attribute__((address_space(3))) uint32_t*)l, 16, 0, 0);
}

__device__ __forceinline__ bf16x8 cvt8(const float* __restrict__ s) {
  const float4 a = *(const float4*)s, b = *(const float4*)(s + 4);
  bf16x8 o;
  o[0] = (bf16)a.x; o[1] = (bf16)a.y; o[2] = (bf16)a.z; o[3] = (bf16)a.w;
  o[4] = (bf16)b.x; o[5] = (bf16)b.y; o[6] = (bf16)b.z; o[7] = (bf16)b.w;
  return o;
}

// ---------------------------------------------------------------- mega-prep: weight casts + input projection
// blocks [0, 6912): in/out proj weights fp32->bf16, 8 elems/thread (float4 x2 -> bf16x8 16B store)
// blocks [6912, 7296): x_proj weight pad 80->128 rows, 8 elems/thread
// blocks [7296, 19584): input projection (K=12) -> h, 1 elem/thread
__global__ __launch_bounds__(256) void prep_k(const float* __restrict__ win, const float* __restrict__ wout,
                                              const float* __restrict__ wxp,
                                              const float* __restrict__ x, const float* __restrict__ inw,
                                              const float* __restrict__ inb,
                                              bf16* __restrict__ bin, bf16* __restrict__ bout,
                                              bf16* __restrict__ bxp, float* __restrict__ h) {
  const int blk = blockIdx.x;
  if (blk < 6912) {
    const int i8 = blk * 2048 + threadIdx.x * 8;        // NIN = 9437184 = 4608 blocks exactly
    const int NIN = 4 * 3072 * 768;
    if (i8 < NIN) *(bf16x8*)&bin[i8] = cvt8(win + i8);
    else          *(bf16x8*)&bout[i8 - NIN] = cvt8(wout + (i8 - NIN));
  } else if (blk < 7296) {
    const int i8 = (blk - 6912) * 2048 + threadIdx.x * 8;   // 4*128*1536; 8 elems same row
    const int k = i8 % 1536;
    const int r = (i8 / 1536) % XP_N;
    const int l = i8 / (1536 * XP_N);
    if (r < 80) *(bf16x8*)&bxp[i8] = cvt8(wxp + ((size_t)l * 80 + r) * 1536 + k);
    else        *(bf16x8*)&bxp[i8] = (bf16x8){(bf16)0.f, (bf16)0.f, (bf16)0.f, (bf16)0.f,
                                              (bf16)0.f, (bf16)0.f, (bf16)0.f, (bf16)0.f};
  } else {
    const int idx = (blk - 7296) * 256 + threadIdx.x;   // NTOK*768
    const int d = idx % D_MODEL;
    const int t = idx / D_MODEL;
    float acc = inb[d];
    #pragma unroll
    for (int f = 0; f < 12; ++f) acc = fmaf(x[t * 12 + f], inw[d * 12 + f], acc);
    h[idx] = acc;
  }
}

// ---------------------------------------------------------------- rmsnorm -> bf16
__global__ __launch_bounds__(256) void rmsnorm_k(const float* __restrict__ h, const float* __restrict__ lnw,
                                                 bf16* __restrict__ xn) {
  const int t = blockIdx.x;
  const float* __restrict__ hr = h + (size_t)t * D_MODEL;
  float v[3];
  float ss = 0.f;
  #pragma unroll
  for (int i = 0; i < 3; ++i) { v[i] = hr[threadIdx.x + i * 256]; ss = fmaf(v[i], v[i], ss); }
  #pragma unroll
  for (int o = 32; o > 0; o >>= 1) ss += __shfl_down(ss, o, 64);
  __shared__ float red[4];
  if ((threadIdx.x & 63) == 0) red[threadIdx.x >> 6] = ss;
  __syncthreads();
  const float tot = red[0] + red[1] + red[2] + red[3];
  const float rs = rsqrtf(tot / (float)D_MODEL + EPS);
  #pragma unroll
  for (int i = 0; i < 3; ++i) {
    const int d = threadIdx.x + i * 256;
    xn[(size_t)t * D_MODEL + d] = (bf16)(v[i] * rs * lnw[d]);
  }
}

// ---------------------------------------------------------------- bf16 MFMA GEMM: C[4096,N] (+)= A[4096,K] @ B[N,K]^T
// m97 layout, BK=64: two 128x32 half-tiles per matrix staged per barrier pair
// (second half at +8KB), 32 MFMAs per iter -> half the vmcnt(0)+barrier drains.
// MODE: 1 = bf16 overwrite, 2 = fp32 atomicAdd (split-K via blockIdx.z). kLen % 64 == 0.
template <int MODE>
__global__ __launch_bounds__(256) void gemm_bt(const bf16* __restrict__ A, const bf16* __restrict__ B,
                                               void* __restrict__ Cv, const int N, const int K, const int kLen) {
  alignas(16) __shared__ bf16 As[2 * 128 * 32];    // [half][128][32]
  alignas(16) __shared__ bf16 Bs[2 * 128 * 32];
  const int tid = threadIdx.x;
  const int lane = tid & 63;
  const int wid = tid >> 6;
  const int wm = wid & 1, wn = wid >> 1;
  const int m0 = blockIdx.x * 128, n0 = blockIdx.y * 128;
  const int kOff = blockIdx.z * kLen;

  floatx4 acc[4][4];
  #pragma unroll
  for (int i = 0; i < 4; ++i)
    #pragma unroll
    for (int j = 0; j < 4; ++j) acc[i][j] = (floatx4){0.f, 0.f, 0.f, 0.f};

  const int srow = lane >> 2;          // staging: row within 16-row segment
  const int skp  = (lane & 3) * 8;     // staging: k offset (8 bf16 = 16B)
  const int fr = lane & 15;            // fragment row
  const int fk = (lane >> 4) * 8;      // fragment k

  for (int k0 = 0; k0 < kLen; k0 += 64) {
    __syncthreads();                   // all waves done reading LDS from prev iter
    #pragma unroll
    for (int h = 0; h < 2; ++h) {      // two k-halves, each the proven 128x32 layout
      #pragma unroll
      for (int i = 0; i < 2; ++i) {
        const int seg = wid * 2 + i;   // 8 segments x 1KB per half-matrix
        const int row = seg * 16 + srow;
        const int kg = kOff + k0 + h * 32 + skp;
        async_ld16(A + (size_t)(m0 + row) * K + kg, (char*)As + h * 8192 + seg * 1024);
        async_ld16(B + (size_t)(n0 + row) * K + kg, (char*)Bs + h * 8192 + seg * 1024);
      }
    }
    __syncthreads();                   // compiler drains vmcnt(0) before barrier
    #pragma unroll
    for (int h = 0; h < 2; ++h) {
      bf16x8 a[4], b[4];
      #pragma unroll
      for (int t = 0; t < 4; ++t) {
        a[t] = *(const bf16x8*)&As[h * 4096 + (wm * 64 + t * 16 + fr) * 32 + fk];
        b[t] = *(const bf16x8*)&Bs[h * 4096 + (wn * 64 + t * 16 + fr) * 32 + fk];
      }
      #pragma unroll
      for (int i = 0; i < 4; ++i)
        #pragma unroll
        for (int j = 0; j < 4; ++j)
          acc[i][j] = __builtin_amdgcn_mfma_f32_16x16x32_bf16(a[i], b[j], acc[i][j], 0, 0, 0);
    }
  }

  const int quad = lane >> 4, col = lane & 15;
  #pragma unroll
  for (int i = 0; i < 4; ++i)
    #pragma unroll
    for (int j = 0; j < 4; ++j) {
      const int gm0 = m0 + wm * 64 + i * 16 + quad * 4;
      const int gn  = n0 + wn * 64 + j * 16 + col;
      #pragma unroll
      for (int r = 0; r < 4; ++r) {
        const size_t off = (size_t)(gm0 + r) * N + gn;
        const float v = acc[i][j][r];
        if (MODE == 1) ((bf16*)Cv)[off] = (bf16)v;
        else           atomicAdd(&((float*)Cv)[off], v);
      }
    }
}

// ---------------------------------------------------------------- causal depthwise conv4 + silu (bf16 in/out)
// blocks [0,512) additionally zero the dbc accumulator (2 MB) for the following split-K GEMM.
__global__ __launch_bounds__(256) void conv_silu_k(const bf16* __restrict__ xz, const float* __restrict__ cw,
                                                   const float* __restrict__ cb, bf16* __restrict__ xxb,
                                                   float* __restrict__ dbc) {
  if (blockIdx.x < 512) {
    const int z = blockIdx.x * 256 + threadIdx.x;      // 131072 float4 = 2 MB
    ((float4*)dbc)[z] = (float4){0.f, 0.f, 0.f, 0.f};
  }
  const int idx = blockIdx.x * 256 + threadIdx.x;   // NTOK*1536
  const int d = idx % D_INNER;
  const int bt = idx / D_INNER;
  const int t = bt & (TSEQ - 1);
  float acc = cb[d];
  #pragma unroll
  for (int j = 0; j < 4; ++j) {
    const int tt = t - 3 + j;
    if (tt >= 0) acc = fmaf((float)xz[(size_t)(bt - 3 + j) * (2 * D_INNER) + d], cw[d * 4 + j], acc);
  }
  xxb[idx] = (bf16)silu_f(acc);
}

// ---------------------------------------------------------------- chunked selective scan, phase 1 (+fused dt_proj):
// packed-fp32 (v_pk_fma_f32) version. per chunk: su = sum du_t, S[n] local state; stores delta for p3.
// Fast path exploits A_log = log(1..16) => A_n = -(n+1): e_n = r^(n+1), pairs E_k=(r^{2k+1},r^{2k+2}).
__global__ __launch_bounds__(256) void scan_p1_k(const bf16* __restrict__ xxb, const float* __restrict__ dbc,
                                                 const float* __restrict__ dtw, const float* __restrict__ dtb,
                                                 const float* __restrict__ Alog,
                                                 float* __restrict__ S, float* __restrict__ su,
                                                 float* __restrict__ delta) {
  const int c = blockIdx.x;
  const int d = blockIdx.y * 256 + threadIdx.x;
  const int b = blockIdx.z;
  f32x2 w2[24];
  #pragma unroll
  for (int k = 0; k < 12; ++k) {
    const float4 t4 = *(const float4*)&dtw[(size_t)d * DT_RANK + k * 4];
    w2[2 * k]     = (f32x2){t4.x, t4.y};
    w2[2 * k + 1] = (f32x2){t4.z, t4.w};
  }
  const float bias = dtb[d];
  float A[16];
  bool fast = true;
  #pragma unroll
  for (int n = 0; n < 16; ++n) {
    A[n] = -__expf(Alog[(size_t)d * 16 + n]);
    fast = fast && (__builtin_fabsf(A[n] + (float)(n + 1)) < 1e-3f);
  }
  f32x2 S2[8];
  #pragma unroll
  for (int k = 0; k < 8; ++k) S2[k] = (f32x2){0.f, 0.f};
  float sus = 0.f;
  const int bt0 = b * TSEQ + c * CHUNK;
  if (fast) {
    for (int tt = 0; tt < CHUNK; ++tt) {
      const size_t bt = bt0 + tt;
      const float* __restrict__ db = dbc + bt * XP_N;             // wave-uniform -> s_load
      f32x2 acc2 = (f32x2){bias, 0.f};
      #pragma unroll
      for (int k = 0; k < 24; ++k) acc2 += *(const f32x2*)&db[2 * k] * w2[k];   // v_pk_fma_f32
      const float du = softplus_f(acc2.x + acc2.y);
      delta[bt * D_INNER + d] = du;
      sus += du;
      const float xv  = (float)xxb[bt * D_INNER + d];
      const float dux = du * xv;
      const f32x2 dux2 = (f32x2){dux, dux};
      const float r  = __expf(-du);
      const float rr = r * r;
      f32x2 E = (f32x2){r, rr};
      const f32x2 F = (f32x2){rr, rr};
      const f32x2* __restrict__ B2 = (const f32x2*)(db + DT_RANK);
      #pragma unroll
      for (int k = 0; k < 8; ++k) {
        S2[k] = E * S2[k] + dux2 * B2[k];
        E *= F;
      }
    }
  } else {
    for (int tt = 0; tt < CHUNK; ++tt) {
      const size_t bt = bt0 + tt;
      const float* __restrict__ db = dbc + bt * XP_N;
      float dacc = bias;
      #pragma unroll
      for (int k = 0; k < 24; ++k) { dacc = fmaf(db[2*k], w2[k].x, dacc); dacc = fmaf(db[2*k+1], w2[k].y, dacc); }
      const float du = softplus_f(dacc);
      delta[bt * D_INNER + d] = du;
      sus += du;
      const float xv  = (float)xxb[bt * D_INNER + d];
      const float dux = du * xv;
      const float* __restrict__ Bp = db + DT_RANK;
      #pragma unroll
      for (int n = 0; n < 16; ++n) {
        float* sv = (float*)&S2[n >> 1];
        sv[n & 1] = fmaf(__expf(du * A[n]), sv[n & 1], dux * Bp[n]);
      }
    }
  }
  const size_t base = ((size_t)(b * NCHUNK + c) * 16) * D_INNER + d;
  #pragma unroll
  for (int n = 0; n < 16; ++n) S[base + (size_t)n * D_INNER] = ((const float*)&S2[n >> 1])[n & 1];
  su[(size_t)(b * NCHUNK + c) * D_INNER + d] = sus;
}

// ---------------------------------------------------------------- phase 2: sequential chunk-prefix fold
// one thread per (b, n, d); P_c = exp(A_n * su_c) (math identity); S <- Hin in place.
__global__ __launch_bounds__(256) void scan_fold_k(const float* __restrict__ Alog, const float* __restrict__ su,
                                                   float* __restrict__ S) {
  const int idx = blockIdx.x * 256 + threadIdx.x;       // NB*16*D_INNER = 98304
  const int d = idx % D_INNER;
  const int bn = idx / D_INNER;
  const int n = bn & 15;
  const int b = bn >> 4;
  const float A = -__expf(Alog[(size_t)d * 16 + n]);
  float H = 0.f;
  #pragma unroll 4
  for (int c = 0; c < NCHUNK; ++c) {
    const size_t off = ((size_t)((b * NCHUNK + c) * 16 + n)) * D_INNER + d;
    const float Pv = __expf(A * su[(size_t)(b * NCHUNK + c) * D_INNER + d]);
    const float Sv = S[off];
    S[off] = H;                       // S becomes Hin (incoming state for chunk c)
    H = fmaf(Pv, H, Sv);
  }
}

// phase 3: packed-fp32 replay with incoming state + precomputed delta; fuse D-skip + silu(z) gate; emit bf16
__global__ __launch_bounds__(256) void scan_p3_k(const bf16* __restrict__ xxb, const float* __restrict__ dbc,
                                                 const float* __restrict__ delta, const float* __restrict__ Alog,
                                                 const float* __restrict__ Hin,
                                                 const bf16* __restrict__ xz, const float* __restrict__ Dsk,
                                                 bf16* __restrict__ yg) {
  const int c = blockIdx.x;
  const int d = blockIdx.y * 256 + threadIdx.x;
  const int b = blockIdx.z;
  const size_t hbase = ((size_t)(b * NCHUNK + c) * 16) * D_INNER + d;
  float A[16];
  f32x2 H2[8];
  bool fast = true;
  #pragma unroll
  for (int n = 0; n < 16; ++n) {
    A[n] = -__expf(Alog[(size_t)d * 16 + n]);
    fast = fast && (__builtin_fabsf(A[n] + (float)(n + 1)) < 1e-3f);
    ((float*)&H2[n >> 1])[n & 1] = Hin[hbase + (size_t)n * D_INNER];
  }
  const float dsk = Dsk[d];
  const int bt0 = b * TSEQ + c * CHUNK;
  if (fast) {
    for (int tt = 0; tt < CHUNK; ++tt) {
      const size_t bt = bt0 + tt;
      const float du  = delta[bt * D_INNER + d];
      const float xv  = (float)xxb[bt * D_INNER + d];
      const float dux = du * xv;
      const f32x2 dux2 = (f32x2){dux, dux};
      const float* __restrict__ db = dbc + bt * XP_N;             // wave-uniform -> s_load
      const f32x2* __restrict__ B2 = (const f32x2*)(db + DT_RANK);
      const f32x2* __restrict__ C2 = (const f32x2*)(db + DT_RANK + 16);
      const float r  = __expf(-du);
      const float rr = r * r;
      f32x2 E = (f32x2){r, rr};
      const f32x2 F = (f32x2){rr, rr};
      f32x2 y2 = (f32x2){0.f, 0.f};
      #pragma unroll
      for (int k = 0; k < 8; ++k) {
        H2[k] = E * H2[k] + dux2 * B2[k];
        y2 = H2[k] * C2[k] + y2;
        E *= F;
      }
      const float y = y2.x + y2.y;
      const float z = (float)xz[bt * (2 * D_INNER) + D_INNER + d];
      yg[bt * D_INNER + d] = (bf16)((y + dsk * xv) * silu_f(z));
    }
  } else {
    for (int tt = 0; tt < CHUNK; ++tt) {
      const size_t bt = bt0 + tt;
      const float du  = delta[bt * D_INNER + d];
      const float xv  = (float)xxb[bt * D_INNER + d];
      const float dux = du * xv;
      const float* __restrict__ db = dbc + bt * XP_N;
      const float* __restrict__ Bp = db + DT_RANK;
      const float* __restrict__ Cp = db + DT_RANK + 16;
      float y = 0.f;
      #pragma unroll
      for (int n = 0; n < 16; ++n) {
        float* hv = (float*)&H2[n >> 1];
        hv[n & 1] = fmaf(__expf(du * A[n]), hv[n & 1], dux * Bp[n]);
        y = fmaf(hv[n & 1], Cp[n], y);
      }
      const float z = (float)xz[bt * (2 * D_INNER) + D_INNER + d];
      yg[bt * D_INNER + d] = (bf16)((y + dsk * xv) * silu_f(z));
    }
  }
}

// ---------------------------------------------------------------- final rmsnorm + head dot
__global__ __launch_bounds__(256) void final_k(const float* __restrict__ h, const float* __restrict__ nw,
                                               const float* __restrict__ hw, const float* __restrict__ hb,
                                               float* __restrict__ out) {
  const int t = blockIdx.x;
  const float* __restrict__ hr = h + (size_t)t * D_MODEL;
  float ss = 0.f, dt_ = 0.f;
  #pragma unroll
  for (int i = 0; i < 3; ++i) {
    const int d = threadIdx.x + i * 256;
    const float v = hr[d];
    ss  = fmaf(v, v, ss);
    dt_ = fmaf(v, nw[d] * hw[d], dt_);
  }
  #pragma unroll
  for (int o = 32; o > 0; o >>= 1) { ss += __shfl_down(ss, o, 64); dt_ += __shfl_down(dt_, o, 64); }
  __shared__ float r0[4], r1[4];
  if ((threadIdx.x & 63) == 0) { r0[threadIdx.x >> 6] = ss; r1[threadIdx.x >> 6] = dt_; }
  __syncthreads();
  if (threadIdx.x == 0) {
    const float sst = r0[0] + r0[1] + r0[2] + r0[3];
    const float dtt = r1[0] + r1[1] + r1[2] + r1[3];
    out[t] = dtt * rsqrtf(sst / (float)D_MODEL + EPS) + hb[0];
  }
}

// ---------------------------------------------------------------- host orchestration
extern "C" void kernel_launch(void* const* d_in, const int* in_sizes, int n_in,
                              void* d_out, int out_size, void* d_ws, size_t ws_size,
                              hipStream_t stream) {
  (void)in_sizes; (void)n_in; (void)out_size; (void)ws_size;
  const float* x     = (const float*)d_in[0];
  const float* inpw  = (const float*)d_in[1];
  const float* inpb  = (const float*)d_in[2];
  const float* inprj = (const float*)d_in[3];
  const float* convw = (const float*)d_in[4];
  const float* convb = (const float*)d_in[5];
  const float* xprjw = (const float*)d_in[6];
  const float* dtw   = (const float*)d_in[7];
  const float* dtb   = (const float*)d_in[8];
  const float* alog  = (const float*)d_in[9];
  const float* dskip = (const float*)d_in[10];
  const float* outw  = (const float*)d_in[11];
  const float* lnw   = (const float*)d_in[12];
  const float* normw = (const float*)d_in[13];
  const float* headw = (const float*)d_in[14];
  const float* headb = (const float*)d_in[15];
  float* out = (float*)d_out;

  // workspace layout
  char* p = (char*)d_ws;
  auto take = [&](size_t bytes) { char* q = p; p += (bytes + 255) & ~(size_t)255; return q; };
  bf16*  wbin  = (bf16*) take((size_t)4 * 3072 * 768 * 2);
  bf16*  wbout = (bf16*) take((size_t)4 * 768 * 1536 * 2);
  bf16*  wbxp  = (bf16*) take((size_t)4 * XP_N * 1536 * 2);
  float* h     = (float*)take((size_t)NTOK * D_MODEL * 4);
  bf16*  xn    = (bf16*) take((size_t)NTOK * D_MODEL * 2);
  bf16*  xzb   = (bf16*) take((size_t)NTOK * 2 * D_INNER * 2);
  bf16*  xxb   = (bf16*) take((size_t)NTOK * D_INNER * 2);
  float* dbc   = (float*)take((size_t)NTOK * XP_N * 4);
  float* dlt   = (float*)take((size_t)NTOK * D_INNER * 4);
  float* Sb    = (float*)take((size_t)NB * NCHUNK * 16 * D_INNER * 4);   // becomes Hin in fold
  float* su    = (float*)take((size_t)NB * NCHUNK * D_INNER * 4);
  bf16*  yg    = (bf16*) take((size_t)NTOK * D_INNER * 2);

  prep_k<<<19584, 256, 0, stream>>>(inprj, outw, xprjw, x, inpw, inpb, wbin, wbout, wbxp, h);

  for (int l = 0; l < 4; ++l) {
    rmsnorm_k<<<NTOK, 256, 0, stream>>>(h, lnw + l * D_MODEL, xn);
    gemm_bt<1><<<dim3(32, 24, 1), 256, 0, stream>>>(xn, wbin + (size_t)l * 3072 * 768, xzb, 3072, 768, 768);
    conv_silu_k<<<NTOK * D_INNER / 256, 256, 0, stream>>>(xzb, convw + l * D_INNER * 4, convb + l * D_INNER,
                                                          xxb, dbc);
    gemm_bt<2><<<dim3(32, 1, 8), 256, 0, stream>>>(xxb, wbxp + (size_t)l * XP_N * 1536, dbc, XP_N, 1536, 192);
    scan_p1_k<<<dim3(NCHUNK, 6, NB), 256, 0, stream>>>(xxb, dbc, dtw + (size_t)l * D_INNER * DT_RANK,
                                                       dtb + l * D_INNER, alog + (size_t)l * D_INNER * 16,
                                                       Sb, su, dlt);
    scan_fold_k<<<NB * 16 * D_INNER / 256, 256, 0, stream>>>(alog + (size_t)l * D_INNER * 16, su, Sb);
    scan_p3_k<<<dim3(NCHUNK, 6, NB), 256, 0, stream>>>(xxb, dbc, dlt, alog + (size_t)l * D_INNER * 16,
                                                       Sb, xzb, dskip + l * D_INNER, yg);
    gemm_bt<2><<<dim3(32, 6, 2), 256, 0, stream>>>(yg, wbout + (size_t)l * 768 * 1536, h, 768, 1536, 768);
  }

  final_k<<<NTOK, 256, 0, stream>>>(h, normw, headw, headb, out);
}